// Round 10
// baseline (3026.689 us; speedup 1.0000x reference)
//
#include <hip/hip_runtime.h>
#include <cstdint>
#include <cstddef>

// Keep ALL device FP math un-contracted (no implicit FMA) so FPS/kNN
// distance bits match the XLA-CPU reference exactly. Where FMA is wanted
// (conv inner loop, kNN dot) it is written explicitly with fmaf().
#pragma clang fp contract(off)

#define NB 8
#define NP 8192
#define NM 2048
#define NK 16
#define NCIN 64
#define NCF 67      // 3 + CIN
#define NCOUT 128
#define FTP 80      // padded feat_t row (floats), 320B aligned
typedef unsigned long long ull;

// DPP-based wave64 f32 max reduce step: pure VALU (no LDS pipe).
template <int CTRL>
__device__ __forceinline__ float dpp_fmax(float v) {
  int o = __builtin_amdgcn_update_dpp(__float_as_int(v), __float_as_int(v),
                                      CTRL, 0xf, 0xf, false);
  return fmaxf(v, __int_as_float(o));
}
// After these 6 steps lane 63 holds max over all 64 lanes.
__device__ __forceinline__ float wave_fmax_to_lane63(float v) {
  v = dpp_fmax<0x111>(v);  // row_shr:1
  v = dpp_fmax<0x112>(v);  // row_shr:2
  v = dpp_fmax<0x114>(v);  // row_shr:4
  v = dpp_fmax<0x118>(v);  // row_shr:8
  v = dpp_fmax<0x142>(v);  // row_bcast15
  v = dpp_fmax<0x143>(v);  // row_bcast31
  return v;
}

// ---------------------------------------------------------------- FPS role
// Round-4 fps_kernel VERBATIM (measured best: 2006 us; 3-array LDS, single
// barrier/iter, DPP value max + ballot first-lane argmax, u64 parity slots).
__device__ void fps_role(char* smem, int b, const float* __restrict__ xyz,
                         float* __restrict__ out_xyz) {
  float* sx = (float*)smem;
  float* sy = sx + NP;
  float* sz = sy + NP;
  ull* slot = (ull*)(sz + NP);   // [2][8]
  const int t = threadIdx.x;
  const float* P = xyz + (size_t)b * NP * 3;
  for (int i = t; i < NP; i += 512) {
    sx[i] = P[i * 3 + 0];
    sy[i] = P[i * 3 + 1];
    sz[i] = P[i * 3 + 2];
  }
  __syncthreads();
  float px[16], py[16], pz[16], dv[16];
  const int n0 = t * 16;
#pragma unroll
  for (int j = 0; j < 16; ++j) {
    px[j] = sx[n0 + j]; py[j] = sy[n0 + j]; pz[j] = sz[n0 + j];
    dv[j] = 1e10f;
  }
  int cur = 0;
  const int wid = t >> 6;
  const int lane = t & 63;
  float* outb = out_xyz + (size_t)b * NM * 3;
  for (int it = 0; it < NM; ++it) {
    const float cx = sx[cur], cy = sy[cur], cz = sz[cur];
    if (t == 0) {
      outb[it * 3 + 0] = cx;
      outb[it * 3 + 1] = cy;
      outb[it * 3 + 2] = cz;
    }
    float bv = -1.0f;
    int bn = 0;
#pragma unroll
    for (int j = 0; j < 16; ++j) {
      float dx = px[j] - cx, dy = py[j] - cy, dz = pz[j] - cz;
      float d = dx * dx + dy * dy;   // contract(off): separate mul/add
      d = d + dz * dz;
      float nd = fminf(dv[j], d);
      dv[j] = nd;
      bool gt = nd > bv;             // strict > keeps earliest (lowest n) on ties
      bv = gt ? nd : bv;
      bn = gt ? (n0 + j) : bn;
    }
    float wtop = wave_fmax_to_lane63(bv);
    float wmax = __int_as_float(__builtin_amdgcn_readlane(__float_as_int(wtop), 63));
    ull mset = __ballot(bv == wmax);
    int winlane = (int)(__ffsll(mset) - 1);
    int wn = __builtin_amdgcn_readlane(bn, winlane);
    if (lane == 0)
      slot[(it & 1) * 8 + wid] = (((ull)__float_as_uint(wmax)) << 32) | (unsigned)wn;
    __syncthreads();
    ull sv = slot[(it & 1) * 8 + (lane & 7)];
    float v2 = __uint_as_float((unsigned)(sv >> 32));
    int n2 = (int)(unsigned)(sv & 0xffffffffu);
    float gtop = wave_fmax_to_lane63(v2);
    float gmax = __int_as_float(__builtin_amdgcn_readlane(__float_as_int(gtop), 63));
    ull ms2 = __ballot(v2 == gmax);
    int wslot = (int)(__ffsll(ms2) - 1);
    cur = __builtin_amdgcn_readlane(n2, wslot);
  }
}

// ----------------------------------------------- transpose role (512 thr)
// feat_t[b][n][0..2]=xyz, [3..66]=features[:,n], [67..79]=0
__device__ void transpose_role(char* smem, int blk, const float* __restrict__ xyz,
                               const float* __restrict__ feats,
                               float* __restrict__ feat_t) {
  float (*tile)[81] = (float (*)[81])smem;  // 64x81, +1 pad
  const int b = blk >> 7;
  const int n0 = (blk & 127) << 6;
  const int t = threadIdx.x;
  if (t < 192) {
    float v = xyz[((size_t)b * NP + n0) * 3 + t];
    tile[t / 3][t % 3] = v;
  }
  const int cr = t >> 6;   // 0..7
  const int ln = t & 63;
  for (int c = cr; c < NCIN; c += 8) {
    tile[ln][3 + c] = feats[((size_t)b * NCIN + c) * NP + n0 + ln];
  }
  __syncthreads();
  float* dst = feat_t + ((size_t)b * NP + n0) * FTP;
  for (int i = t; i < 64 * FTP; i += 512) {
    int r = i / FTP, cc = i - r * FTP;
    dst[i] = (cc < NCF) ? tile[r][cc] : 0.0f;
  }
}

// ------------------------------------------------------ W transpose role
__device__ void wtrans_role(const float* __restrict__ W, float* __restrict__ Wt) {
  for (int i = threadIdx.x; i < NCF * NCOUT; i += 512) {
    int j = i >> 7, c = i & 127;
    Wt[i] = W[c * NCF + j];
  }
}

// --------------------------------------- prep: fps + transpose + wtrans
// Roles by blockIdx, ZERO inter-block communication (round-8 lesson: any
// cross-block protocol is radioactive under graph replay; independent
// co-scheduling is safe). fps blocks are 0..7 -> dispatched first; the
// 1024 transpose blocks + wtrans fill the other CUs and finish (~40us)
// well inside fps's ~2ms shadow.
__global__ __launch_bounds__(512) void prep_kernel(
    const float* __restrict__ xyz, const float* __restrict__ feats,
    const float* __restrict__ W, float* __restrict__ out_xyz,
    float* __restrict__ feat_t, float* __restrict__ Wt) {
  __shared__ __align__(16) char smem[98432];  // fps: 96KB coords + 128B slots
  const int bi = blockIdx.x;
  if (bi < 8) {
    fps_role(smem, bi, xyz, out_xyz);
  } else if (bi < 8 + NB * 128) {
    transpose_role(smem, bi - 8, xyz, feats, feat_t);
  } else {
    wtrans_role(W, Wt);
  }
}

// ---------------------------------------------------------------- kNN
// 4 lanes per query (16 queries/wave, 64/block): each lane scans points
// p === s (mod 4) -> 2048 pts/lane, so the divergent sorted-insert cost
// (~16*ln coverage window) amortizes over 8x more points than the old
// 64-lane/query layout. Distance math bit-identical; exact top-16 set via
// the same u64 (d-bits, idx) ordering; width-4 shuffle merge is exact
// (keys unique, global min each round).
// LDS inner reads: one address per sub-lane s, broadcast to 16 lanes ->
// 4 consecutive banks, conflict-free.
__global__ __launch_bounds__(256) void knn_kernel(const float* __restrict__ xyz,
                                                  const float* __restrict__ new_xyz,
                                                  int* __restrict__ knn_idx) {
  __shared__ float tx_[1024], ty_[1024], tz_[1024], tp2_[1024];
  const int bq = blockIdx.x;           // 256 blocks
  const int b = bq >> 5;
  const int m0 = (bq & 31) << 6;       // 64 queries per block
  const int t = threadIdx.x;
  const int wv = t >> 6;
  const int lane = t & 63;
  const int ql = lane >> 2;            // 0..15
  const int s = lane & 3;
  const int m = m0 + wv * 16 + ql;
  const float* P = xyz + (size_t)b * NP * 3;
  const float* T = new_xyz + ((size_t)b * NM + m) * 3;
  const float qx = T[0], qy = T[1], qz = T[2];
  float q2 = qx * qx + qy * qy;
  q2 = q2 + qz * qz;
  ull r[16];
#pragma unroll
  for (int i = 0; i < 16; ++i) r[i] = ~0ull;
  for (int tile = 0; tile < 8; ++tile) {
    __syncthreads();
    for (int i = t; i < 3072; i += 256) {
      float v = P[tile * 3072 + i];
      int pt = i / 3, dc = i - pt * 3;
      float* dstp = (dc == 0) ? tx_ : ((dc == 1) ? ty_ : tz_);
      dstp[pt] = v;
    }
    __syncthreads();
    for (int i = t; i < 1024; i += 256) {
      float ax = tx_[i], ay = ty_[i], az = tz_[i];
      float p2 = ax * ax + ay * ay;    // same order as reference |p|^2
      p2 = p2 + az * az;
      tp2_[i] = p2;
    }
    __syncthreads();
    for (int i = 0; i < 256; ++i) {
      int p = (i << 2) + s;
      float px = tx_[p], py = ty_[p], pz = tz_[p];
      float p2 = tp2_[p];
      float dot = fmaf(pz, qz, fmaf(py, qy, px * qx));
      float s1 = q2 + p2;
      float s2 = 2.0f * dot;
      float d = s1 - s2;
      unsigned db = __float_as_uint(d);
      db = ((int)db < 0) ? ~db : (db | 0x80000000u);  // monotone map (d can round < 0)
      ull key = ((ull)db << 32) | (unsigned)(tile * 1024 + p);
      if (key < r[15]) {
#pragma unroll
        for (int q = 0; q < 16; ++q) {
          ull lo = (key < r[q]) ? key : r[q];
          ull hi = (key < r[q]) ? r[q] : key;
          r[q] = lo;
          key = hi;
        }
      }
    }
  }
  // merge 4 sorted lists of 16 (sub-lanes of each query) -> global top-16
  const int out_base = ((b * NM + m) << 4);
#pragma unroll 1
  for (int k = 0; k < NK; ++k) {
    ull best = r[0];
    ull o = __shfl_xor(best, 1, 64); best = (o < best) ? o : best;
    o = __shfl_xor(best, 2, 64);     best = (o < best) ? o : best;
    if (s == 0) knn_idx[out_base + k] = (int)(unsigned)(best & 0xffffffffu);
    if (r[0] == best) {  // unique keys: exactly one winner advances
#pragma unroll
      for (int q = 0; q < 15; ++q) r[q] = r[q + 1];
      r[15] = ~0ull;
    }
  }
}

// ------------------------------------------- gather + 1x1 conv + minmax + stats
// Block: 8 m's (128 neighbor columns). LDS: Wt[67][128] + data[68][128].
// partials layout: [c][2048] rows for sum (c<128) and sumsq (128+c),
// so bnstats can do coalesced row reductions.
__global__ __launch_bounds__(256) void conv_kernel(const float* __restrict__ feat_t,
                                                   const int* __restrict__ knn_idx,
                                                   const float* __restrict__ Wt,
                                                   float* __restrict__ ymax,
                                                   float* __restrict__ ymin,
                                                   float* __restrict__ partials) {
  __shared__ float wl[NCF * 128];
  __shared__ float data[68 * 128];
  __shared__ int sidx[128];
  const int blk = blockIdx.x;  // 2048
  const int b = blk >> 8;
  const int m0 = (blk & 255) << 3;
  const int t = threadIdx.x;
  for (int i = t; i < NCF * 128; i += 256) wl[i] = Wt[i];
  if (t < 128) sidx[t] = knn_idx[((b * NM + m0) << 4) + t];
  __syncthreads();
  const int q = t & 3;
  for (int cc = t >> 2; cc < 128; cc += 64) {
    int n = sidx[cc];
    const float* src = feat_t + ((size_t)(b * NP + n)) * FTP + q * 20;
    float4 v0 = ((const float4*)src)[0];
    float4 v1 = ((const float4*)src)[1];
    float4 v2 = ((const float4*)src)[2];
    float4 v3 = ((const float4*)src)[3];
    float4 v4 = ((const float4*)src)[4];
    float vv[20] = {v0.x, v0.y, v0.z, v0.w, v1.x, v1.y, v1.z, v1.w,
                    v2.x, v2.y, v2.z, v2.w, v3.x, v3.y, v3.z, v3.w,
                    v4.x, v4.y, v4.z, v4.w};
    const int jb = q * 20;
#pragma unroll
    for (int u = 0; u < 20; ++u) {
      int j = jb + u;
      if (j < 68) data[j * 128 + cc] = vv[u];
    }
  }
  __syncthreads();
  const int colg = t & 31, cg = t >> 5;
  const int c0 = cg << 4, col0 = colg << 2;
  float acc[16][4];
#pragma unroll
  for (int a = 0; a < 16; ++a)
#pragma unroll
    for (int w = 0; w < 4; ++w) acc[a][w] = 0.0f;
  for (int j = 0; j < NCF; ++j) {
    const float4 dvv = *(const float4*)&data[j * 128 + col0];
    const float4 w0 = *(const float4*)&wl[j * 128 + c0 + 0];
    const float4 w1 = *(const float4*)&wl[j * 128 + c0 + 4];
    const float4 w2 = *(const float4*)&wl[j * 128 + c0 + 8];
    const float4 w3 = *(const float4*)&wl[j * 128 + c0 + 12];
    float wv[16] = {w0.x, w0.y, w0.z, w0.w, w1.x, w1.y, w1.z, w1.w,
                    w2.x, w2.y, w2.z, w2.w, w3.x, w3.y, w3.z, w3.w};
    float dd[4] = {dvv.x, dvv.y, dvv.z, dvv.w};
#pragma unroll
    for (int a = 0; a < 16; ++a)
#pragma unroll
      for (int w = 0; w < 4; ++w) acc[a][w] = fmaf(wv[a], dd[w], acc[a][w]);
  }
  const int mg = m0 + (colg >> 2);
#pragma unroll 1
  for (int a = 0; a < 16; ++a) {
    float x0 = acc[a][0], x1 = acc[a][1], x2 = acc[a][2], x3 = acc[a][3];
    float mx = fmaxf(fmaxf(x0, x1), fmaxf(x2, x3));
    float mn = fminf(fminf(x0, x1), fminf(x2, x3));
    float sm = (x0 + x1) + (x2 + x3);
    float sq = fmaf(x0, x0, fmaf(x1, x1, fmaf(x2, x2, x3 * x3)));
    float o;
    o = __shfl_xor(mx, 1, 64); mx = fmaxf(mx, o);
    o = __shfl_xor(mx, 2, 64); mx = fmaxf(mx, o);
    o = __shfl_xor(mn, 1, 64); mn = fminf(mn, o);
    o = __shfl_xor(mn, 2, 64); mn = fminf(mn, o);
#pragma unroll
    for (int s2 = 1; s2 < 32; s2 <<= 1) {
      sm += __shfl_xor(sm, s2, 64);
      sq += __shfl_xor(sq, s2, 64);
    }
    const int c = c0 + a;
    if ((colg & 3) == 0) {
      ymax[((size_t)b * NCOUT + c) * NM + mg] = mx;
      ymin[((size_t)b * NCOUT + c) * NM + mg] = mn;
    }
    if (colg == 0) {
      partials[(size_t)c * 2048 + blk] = sm;
      partials[(size_t)(128 + c) * 2048 + blk] = sq;
    }
  }
}

// ------------------------------------------------------- BN stats finalize
// 128 blocks (one per channel): coalesced row sums of partials[c][*] and
// partials[128+c][*] in double, LDS tree, then a,b.
__global__ __launch_bounds__(256) void bnstats_kernel(const float* __restrict__ partials,
                                                      const float* __restrict__ gamma,
                                                      const float* __restrict__ beta,
                                                      float* __restrict__ chanAB) {
  __shared__ double sbuf[256];
  const int c = blockIdx.x;
  const int t = threadIdx.x;
  const float* rowS = partials + (size_t)c * 2048;
  const float* rowQ = partials + (size_t)(128 + c) * 2048;
  double a1 = 0.0, a2 = 0.0;
  for (int i = t; i < 2048; i += 256) {
    a1 += (double)rowS[i];
    a2 += (double)rowQ[i];
  }
  sbuf[t] = a1;
  __syncthreads();
  for (int off = 128; off; off >>= 1) {
    if (t < off) sbuf[t] += sbuf[t + off];
    __syncthreads();
  }
  const double sum1 = sbuf[0];
  __syncthreads();
  sbuf[t] = a2;
  __syncthreads();
  for (int off = 128; off; off >>= 1) {
    if (t < off) sbuf[t] += sbuf[t + off];
    __syncthreads();
  }
  const double sum2 = sbuf[0];
  if (t == 0) {
    const double inv = 1.0 / 262144.0;  // B*M*K
    double mean = sum1 * inv;
    double var = sum2 * inv - mean * mean;
    float a = gamma[c] * (float)(1.0 / sqrt(var + 1e-5));
    float bb = beta[c] - (float)mean * a;
    chanAB[c] = a;
    chanAB[128 + c] = bb;
  }
}

// ------------------------------------------------- normalize + relu + pool
// max_k relu(a*y+b) = relu(a*(a>0 ? ymax : ymin) + b)
__global__ __launch_bounds__(256) void final_kernel(const float* __restrict__ ymax,
                                                    const float* __restrict__ ymin,
                                                    const float* __restrict__ chanAB,
                                                    float* __restrict__ out1) {
  const int i = blockIdx.x * 256 + threadIdx.x;
  const int c = (i >> 11) & 127;
  const float a = chanAB[c], bb = chanAB[128 + c];
  const float v = (a > 0.0f) ? ymax[i] : ymin[i];
  out1[i] = fmaxf(fmaf(a, v, bb), 0.0f);
}

extern "C" void kernel_launch(void* const* d_in, const int* in_sizes, int n_in,
                              void* d_out, int out_size, void* d_ws, size_t ws_size,
                              hipStream_t stream) {
  (void)in_sizes; (void)n_in; (void)out_size; (void)ws_size;
  const float* xyz = (const float*)d_in[0];
  const float* feats = (const float*)d_in[1];
  const float* W = (const float*)d_in[2];
  const float* gamma = (const float*)d_in[3];
  const float* beta = (const float*)d_in[4];
  float* out = (float*)d_out;
  float* out_xyz = out;                 // (B,M,3)
  float* out_pooled = out + NB * NM * 3;

  char* ws = (char*)d_ws;
  int* knn_idx = (int*)ws;                                       // 1 MB
  float* feat_t = (float*)(ws + 1048576);                        // 20.97 MB
  float* ymaxp = (float*)(ws + 1048576 + 20971520);              // 8.39 MB
  float* yminp = ymaxp + (size_t)NB * NCOUT * NM;                // 8.39 MB
  float* partials = yminp + (size_t)NB * NCOUT * NM;             // 2 MB (256x2048)
  float* chanAB = partials + 256 * 2048;                         // 1 KB
  float* Wt = chanAB + 256;                                      // 34 KB

  hipLaunchKernelGGL(prep_kernel, dim3(8 + NB * 128 + 1), dim3(512), 0, stream,
                     xyz, feats, W, out_xyz, feat_t, Wt);
  hipLaunchKernelGGL(knn_kernel, dim3(256), dim3(256), 0, stream,
                     xyz, out_xyz, knn_idx);
  hipLaunchKernelGGL(conv_kernel, dim3(2048), dim3(256), 0, stream,
                     feat_t, knn_idx, Wt, ymaxp, yminp, partials);
  hipLaunchKernelGGL(bnstats_kernel, dim3(128), dim3(256), 0, stream,
                     partials, gamma, beta, chanAB);
  hipLaunchKernelGGL(final_kernel, dim3((NB * NCOUT * NM) / 256), dim3(256), 0, stream,
                     ymaxp, yminp, chanAB, out_pooled);
}

// Round 11
// 2743.031 us; speedup vs baseline: 1.1034x; 1.1034x over previous
//
#include <hip/hip_runtime.h>
#include <cstdint>
#include <cstddef>

// Keep ALL device FP math un-contracted (no implicit FMA) so FPS/kNN
// distance bits match the XLA-CPU reference exactly. Where FMA is wanted
// (conv inner loop, kNN dot) it is written explicitly with fmaf().
#pragma clang fp contract(off)

#define NB 8
#define NP 8192
#define NM 2048
#define NK 16
#define NCIN 64
#define NCF 67      // 3 + CIN
#define NCOUT 128
#define FTP 80      // padded feat_t row (floats), 320B aligned
typedef unsigned long long ull;

// DPP-based wave64 f32 max reduce step: pure VALU (no LDS pipe).
template <int CTRL>
__device__ __forceinline__ float dpp_fmax(float v) {
  int o = __builtin_amdgcn_update_dpp(__float_as_int(v), __float_as_int(v),
                                      CTRL, 0xf, 0xf, false);
  return fmaxf(v, __int_as_float(o));
}
// After these 6 steps lane 63 holds max over all 64 lanes.
__device__ __forceinline__ float wave_fmax_to_lane63(float v) {
  v = dpp_fmax<0x111>(v);  // row_shr:1
  v = dpp_fmax<0x112>(v);  // row_shr:2
  v = dpp_fmax<0x114>(v);  // row_shr:4
  v = dpp_fmax<0x118>(v);  // row_shr:8
  v = dpp_fmax<0x142>(v);  // row_bcast15
  v = dpp_fmax<0x143>(v);  // row_bcast31
  return v;
}

// ---------------------------------------------------------------- FPS role
// Round-4 fps_kernel VERBATIM (measured floor ~2006-2035 us; 3-array LDS,
// single barrier/iter, DPP value max + ballot first-lane argmax, u64 parity
// slots). Issue floor is thread-count-invariant (8192 pts x 11 ops / 256
// lanes x 2cyc = 704 cyc/iter); 512 thr measured best for the reduce chain.
__device__ void fps_role(char* smem, int b, const float* __restrict__ xyz,
                         float* __restrict__ out_xyz) {
  float* sx = (float*)smem;
  float* sy = sx + NP;
  float* sz = sy + NP;
  ull* slot = (ull*)(sz + NP);   // [2][8]
  const int t = threadIdx.x;
  const float* P = xyz + (size_t)b * NP * 3;
  for (int i = t; i < NP; i += 512) {
    sx[i] = P[i * 3 + 0];
    sy[i] = P[i * 3 + 1];
    sz[i] = P[i * 3 + 2];
  }
  __syncthreads();
  float px[16], py[16], pz[16], dv[16];
  const int n0 = t * 16;
#pragma unroll
  for (int j = 0; j < 16; ++j) {
    px[j] = sx[n0 + j]; py[j] = sy[n0 + j]; pz[j] = sz[n0 + j];
    dv[j] = 1e10f;
  }
  int cur = 0;
  const int wid = t >> 6;
  const int lane = t & 63;
  float* outb = out_xyz + (size_t)b * NM * 3;
  for (int it = 0; it < NM; ++it) {
    const float cx = sx[cur], cy = sy[cur], cz = sz[cur];
    if (t == 0) {
      outb[it * 3 + 0] = cx;
      outb[it * 3 + 1] = cy;
      outb[it * 3 + 2] = cz;
    }
    float bv = -1.0f;
    int bn = 0;
#pragma unroll
    for (int j = 0; j < 16; ++j) {
      float dx = px[j] - cx, dy = py[j] - cy, dz = pz[j] - cz;
      float d = dx * dx + dy * dy;   // contract(off): separate mul/add
      d = d + dz * dz;
      float nd = fminf(dv[j], d);
      dv[j] = nd;
      bool gt = nd > bv;             // strict > keeps earliest (lowest n) on ties
      bv = gt ? nd : bv;
      bn = gt ? (n0 + j) : bn;
    }
    float wtop = wave_fmax_to_lane63(bv);
    float wmax = __int_as_float(__builtin_amdgcn_readlane(__float_as_int(wtop), 63));
    ull mset = __ballot(bv == wmax);
    int winlane = (int)(__ffsll(mset) - 1);
    int wn = __builtin_amdgcn_readlane(bn, winlane);
    if (lane == 0)
      slot[(it & 1) * 8 + wid] = (((ull)__float_as_uint(wmax)) << 32) | (unsigned)wn;
    __syncthreads();
    ull sv = slot[(it & 1) * 8 + (lane & 7)];
    float v2 = __uint_as_float((unsigned)(sv >> 32));
    int n2 = (int)(unsigned)(sv & 0xffffffffu);
    float gtop = wave_fmax_to_lane63(v2);
    float gmax = __int_as_float(__builtin_amdgcn_readlane(__float_as_int(gtop), 63));
    ull ms2 = __ballot(v2 == gmax);
    int wslot = (int)(__ffsll(ms2) - 1);
    cur = __builtin_amdgcn_readlane(n2, wslot);
  }
}

// ----------------------------------------------- transpose role (512 thr)
// feat_t[b][n][0..2]=xyz, [3..66]=features[:,n], [67..79]=0
__device__ void transpose_role(char* smem, int blk, const float* __restrict__ xyz,
                               const float* __restrict__ feats,
                               float* __restrict__ feat_t) {
  float (*tile)[81] = (float (*)[81])smem;  // 64x81, +1 pad
  const int b = blk >> 7;
  const int n0 = (blk & 127) << 6;
  const int t = threadIdx.x;
  if (t < 192) {
    float v = xyz[((size_t)b * NP + n0) * 3 + t];
    tile[t / 3][t % 3] = v;
  }
  const int cr = t >> 6;   // 0..7
  const int ln = t & 63;
  for (int c = cr; c < NCIN; c += 8) {
    tile[ln][3 + c] = feats[((size_t)b * NCIN + c) * NP + n0 + ln];
  }
  __syncthreads();
  float* dst = feat_t + ((size_t)b * NP + n0) * FTP;
  for (int i = t; i < 64 * FTP; i += 512) {
    int r = i / FTP, cc = i - r * FTP;
    dst[i] = (cc < NCF) ? tile[r][cc] : 0.0f;
  }
}

// ------------------------------------------------------ W transpose role
__device__ void wtrans_role(const float* __restrict__ W, float* __restrict__ Wt) {
  for (int i = threadIdx.x; i < NCF * NCOUT; i += 512) {
    int j = i >> 7, c = i & 127;
    Wt[i] = W[c * NCF + j];
  }
}

// --------------------------------------- prep: fps + transpose + wtrans
// Roles by blockIdx, ZERO inter-block communication (round-8 lesson: any
// cross-block protocol is radioactive under graph replay; independent
// co-scheduling is safe, verified round 10: prep == fps alone at 2020us).
__global__ __launch_bounds__(512) void prep_kernel(
    const float* __restrict__ xyz, const float* __restrict__ feats,
    const float* __restrict__ W, float* __restrict__ out_xyz,
    float* __restrict__ feat_t, float* __restrict__ Wt) {
  __shared__ __align__(16) char smem[98432];  // fps: 96KB coords + 128B slots
  const int bi = blockIdx.x;
  if (bi < 8) {
    fps_role(smem, bi, xyz, out_xyz);
  } else if (bi < 8 + NB * 128) {
    transpose_role(smem, bi - 8, xyz, feats, feat_t);
  } else {
    wtrans_role(W, Wt);
  }
}

// ---------------------------------------------------------------- kNN
// ROUND-9 VERBATIM (measured-good). One wave per query; 4096 blocks -> 8
// blocks/CU, full latency hiding (round-10 lesson: the 4-lane/query variant
// dropped to 1 wave/SIMD and lost ~250us to exposed LDS latency; wave-level
// insert cost is gated by P(any lane inserts), so fewer-lanes-per-query
// saves no issue slots).
__global__ __launch_bounds__(256) void knn_kernel(const float* __restrict__ xyz,
                                                  const float* __restrict__ new_xyz,
                                                  int* __restrict__ knn_idx) {
  __shared__ float tx_[1024], ty_[1024], tz_[1024], tp2_[1024];
  const int b = blockIdx.x >> 9;
  const int m = ((blockIdx.x & 511) << 2) + (threadIdx.x >> 6);
  const int lane = threadIdx.x & 63;
  const float* P = xyz + (size_t)b * NP * 3;
  const float* T = new_xyz + ((size_t)b * NM + m) * 3;
  const float qx = T[0], qy = T[1], qz = T[2];
  float q2 = qx * qx + qy * qy;
  q2 = q2 + qz * qz;
  ull r[16];
#pragma unroll
  for (int i = 0; i < 16; ++i) r[i] = ~0ull;
  for (int tile = 0; tile < 8; ++tile) {
    __syncthreads();
    for (int i = threadIdx.x; i < 3072; i += 256) {
      float v = P[tile * 3072 + i];
      int pt = i / 3, dc = i - pt * 3;
      float* dstp = (dc == 0) ? tx_ : ((dc == 1) ? ty_ : tz_);
      dstp[pt] = v;
    }
    __syncthreads();
    for (int i = threadIdx.x; i < 1024; i += 256) {
      float ax = tx_[i], ay = ty_[i], az = tz_[i];
      float p2 = ax * ax + ay * ay;   // same order as reference |p|^2
      p2 = p2 + az * az;
      tp2_[i] = p2;
    }
    __syncthreads();
    for (int i = 0; i < 16; ++i) {
      int p = (i << 6) + lane;
      float px = tx_[p], py = ty_[p], pz = tz_[p];
      float p2 = tp2_[p];
      float dot = fmaf(pz, qz, fmaf(py, qy, px * qx));
      float s1 = q2 + p2;
      float s2 = 2.0f * dot;
      float d = s1 - s2;
      unsigned db = __float_as_uint(d);
      db = ((int)db < 0) ? ~db : (db | 0x80000000u);  // monotone map (d can round < 0)
      ull key = ((ull)db << 32) | (unsigned)(tile * 1024 + p);
      if (key < r[15]) {
#pragma unroll
        for (int s = 0; s < 16; ++s) {
          ull lo = (key < r[s]) ? key : r[s];
          ull hi = (key < r[s]) ? r[s] : key;
          r[s] = lo;
          key = hi;
        }
      }
    }
  }
  // merge 64 sorted lists of 16 -> global top-16
  const int out_base = ((b * NM + m) << 4);
#pragma unroll 1
  for (int k = 0; k < NK; ++k) {
    ull best = r[0];
#pragma unroll
    for (int s = 1; s < 64; s <<= 1) {
      ull o = __shfl_xor(best, s, 64);
      best = (o < best) ? o : best;
    }
    if (lane == 0) knn_idx[out_base + k] = (int)(unsigned)(best & 0xffffffffu);
    if (r[0] == best) {  // unique keys: exactly one winner advances
#pragma unroll
      for (int s = 0; s < 15; ++s) r[s] = r[s + 1];
      r[15] = ~0ull;
    }
  }
}

// ------------------------------------------- gather + 1x1 conv + minmax + stats
// Block: 8 m's (128 neighbor columns). LDS: Wt[67][128] + data[68][128].
// partials layout: [c][2048] rows (sum c<128, sumsq 128+c) for coalesced
// bnstats reduction.
__global__ __launch_bounds__(256) void conv_kernel(const float* __restrict__ feat_t,
                                                   const int* __restrict__ knn_idx,
                                                   const float* __restrict__ Wt,
                                                   float* __restrict__ ymax,
                                                   float* __restrict__ ymin,
                                                   float* __restrict__ partials) {
  __shared__ float wl[NCF * 128];
  __shared__ float data[68 * 128];
  __shared__ int sidx[128];
  const int blk = blockIdx.x;  // 2048
  const int b = blk >> 8;
  const int m0 = (blk & 255) << 3;
  const int t = threadIdx.x;
  for (int i = t; i < NCF * 128; i += 256) wl[i] = Wt[i];
  if (t < 128) sidx[t] = knn_idx[((b * NM + m0) << 4) + t];
  __syncthreads();
  const int q = t & 3;
  for (int cc = t >> 2; cc < 128; cc += 64) {
    int n = sidx[cc];
    const float* src = feat_t + ((size_t)(b * NP + n)) * FTP + q * 20;
    float4 v0 = ((const float4*)src)[0];
    float4 v1 = ((const float4*)src)[1];
    float4 v2 = ((const float4*)src)[2];
    float4 v3 = ((const float4*)src)[3];
    float4 v4 = ((const float4*)src)[4];
    float vv[20] = {v0.x, v0.y, v0.z, v0.w, v1.x, v1.y, v1.z, v1.w,
                    v2.x, v2.y, v2.z, v2.w, v3.x, v3.y, v3.z, v3.w,
                    v4.x, v4.y, v4.z, v4.w};
    const int jb = q * 20;
#pragma unroll
    for (int u = 0; u < 20; ++u) {
      int j = jb + u;
      if (j < 68) data[j * 128 + cc] = vv[u];
    }
  }
  __syncthreads();
  const int colg = t & 31, cg = t >> 5;
  const int c0 = cg << 4, col0 = colg << 2;
  float acc[16][4];
#pragma unroll
  for (int a = 0; a < 16; ++a)
#pragma unroll
    for (int w = 0; w < 4; ++w) acc[a][w] = 0.0f;
  for (int j = 0; j < NCF; ++j) {
    const float4 dvv = *(const float4*)&data[j * 128 + col0];
    const float4 w0 = *(const float4*)&wl[j * 128 + c0 + 0];
    const float4 w1 = *(const float4*)&wl[j * 128 + c0 + 4];
    const float4 w2 = *(const float4*)&wl[j * 128 + c0 + 8];
    const float4 w3 = *(const float4*)&wl[j * 128 + c0 + 12];
    float wv[16] = {w0.x, w0.y, w0.z, w0.w, w1.x, w1.y, w1.z, w1.w,
                    w2.x, w2.y, w2.z, w2.w, w3.x, w3.y, w3.z, w3.w};
    float dd[4] = {dvv.x, dvv.y, dvv.z, dvv.w};
#pragma unroll
    for (int a = 0; a < 16; ++a)
#pragma unroll
      for (int w = 0; w < 4; ++w) acc[a][w] = fmaf(wv[a], dd[w], acc[a][w]);
  }
  const int mg = m0 + (colg >> 2);
#pragma unroll 1
  for (int a = 0; a < 16; ++a) {
    float x0 = acc[a][0], x1 = acc[a][1], x2 = acc[a][2], x3 = acc[a][3];
    float mx = fmaxf(fmaxf(x0, x1), fmaxf(x2, x3));
    float mn = fminf(fminf(x0, x1), fminf(x2, x3));
    float sm = (x0 + x1) + (x2 + x3);
    float sq = fmaf(x0, x0, fmaf(x1, x1, fmaf(x2, x2, x3 * x3)));
    float o;
    o = __shfl_xor(mx, 1, 64); mx = fmaxf(mx, o);
    o = __shfl_xor(mx, 2, 64); mx = fmaxf(mx, o);
    o = __shfl_xor(mn, 1, 64); mn = fminf(mn, o);
    o = __shfl_xor(mn, 2, 64); mn = fminf(mn, o);
#pragma unroll
    for (int s2 = 1; s2 < 32; s2 <<= 1) {
      sm += __shfl_xor(sm, s2, 64);
      sq += __shfl_xor(sq, s2, 64);
    }
    const int c = c0 + a;
    if ((colg & 3) == 0) {
      ymax[((size_t)b * NCOUT + c) * NM + mg] = mx;
      ymin[((size_t)b * NCOUT + c) * NM + mg] = mn;
    }
    if (colg == 0) {
      partials[(size_t)c * 2048 + blk] = sm;
      partials[(size_t)(128 + c) * 2048 + blk] = sq;
    }
  }
}

// ------------------------------------------------------- BN stats finalize
// 128 blocks (one per channel): coalesced row sums in double, LDS tree.
__global__ __launch_bounds__(256) void bnstats_kernel(const float* __restrict__ partials,
                                                      const float* __restrict__ gamma,
                                                      const float* __restrict__ beta,
                                                      float* __restrict__ chanAB) {
  __shared__ double sbuf[256];
  const int c = blockIdx.x;
  const int t = threadIdx.x;
  const float* rowS = partials + (size_t)c * 2048;
  const float* rowQ = partials + (size_t)(128 + c) * 2048;
  double a1 = 0.0, a2 = 0.0;
  for (int i = t; i < 2048; i += 256) {
    a1 += (double)rowS[i];
    a2 += (double)rowQ[i];
  }
  sbuf[t] = a1;
  __syncthreads();
  for (int off = 128; off; off >>= 1) {
    if (t < off) sbuf[t] += sbuf[t + off];
    __syncthreads();
  }
  const double sum1 = sbuf[0];
  __syncthreads();
  sbuf[t] = a2;
  __syncthreads();
  for (int off = 128; off; off >>= 1) {
    if (t < off) sbuf[t] += sbuf[t + off];
    __syncthreads();
  }
  const double sum2 = sbuf[0];
  if (t == 0) {
    const double inv = 1.0 / 262144.0;  // B*M*K
    double mean = sum1 * inv;
    double var = sum2 * inv - mean * mean;
    float a = gamma[c] * (float)(1.0 / sqrt(var + 1e-5));
    float bb = beta[c] - (float)mean * a;
    chanAB[c] = a;
    chanAB[128 + c] = bb;
  }
}

// ------------------------------------------------- normalize + relu + pool
// max_k relu(a*y+b) = relu(a*(a>0 ? ymax : ymin) + b)
__global__ __launch_bounds__(256) void final_kernel(const float* __restrict__ ymax,
                                                    const float* __restrict__ ymin,
                                                    const float* __restrict__ chanAB,
                                                    float* __restrict__ out1) {
  const int i = blockIdx.x * 256 + threadIdx.x;
  const int c = (i >> 11) & 127;
  const float a = chanAB[c], bb = chanAB[128 + c];
  const float v = (a > 0.0f) ? ymax[i] : ymin[i];
  out1[i] = fmaxf(fmaf(a, v, bb), 0.0f);
}

extern "C" void kernel_launch(void* const* d_in, const int* in_sizes, int n_in,
                              void* d_out, int out_size, void* d_ws, size_t ws_size,
                              hipStream_t stream) {
  (void)in_sizes; (void)n_in; (void)out_size; (void)ws_size;
  const float* xyz = (const float*)d_in[0];
  const float* feats = (const float*)d_in[1];
  const float* W = (const float*)d_in[2];
  const float* gamma = (const float*)d_in[3];
  const float* beta = (const float*)d_in[4];
  float* out = (float*)d_out;
  float* out_xyz = out;                 // (B,M,3)
  float* out_pooled = out + NB * NM * 3;

  char* ws = (char*)d_ws;
  int* knn_idx = (int*)ws;                                       // 1 MB
  float* feat_t = (float*)(ws + 1048576);                        // 20.97 MB
  float* ymaxp = (float*)(ws + 1048576 + 20971520);              // 8.39 MB
  float* yminp = ymaxp + (size_t)NB * NCOUT * NM;                // 8.39 MB
  float* partials = yminp + (size_t)NB * NCOUT * NM;             // 2 MB (256x2048)
  float* chanAB = partials + 256 * 2048;                         // 1 KB
  float* Wt = chanAB + 256;                                      // 34 KB

  hipLaunchKernelGGL(prep_kernel, dim3(8 + NB * 128 + 1), dim3(512), 0, stream,
                     xyz, feats, W, out_xyz, feat_t, Wt);
  hipLaunchKernelGGL(knn_kernel, dim3(NB * 512), dim3(256), 0, stream,
                     xyz, out_xyz, knn_idx);
  hipLaunchKernelGGL(conv_kernel, dim3(2048), dim3(256), 0, stream,
                     feat_t, knn_idx, Wt, ymaxp, yminp, partials);
  hipLaunchKernelGGL(bnstats_kernel, dim3(128), dim3(256), 0, stream,
                     partials, gamma, beta, chanAB);
  hipLaunchKernelGGL(final_kernel, dim3((NB * NCOUT * NM) / 256), dim3(256), 0, stream,
                     ymaxp, yminp, chanAB, out_pooled);
}

// Round 12
// 2579.459 us; speedup vs baseline: 1.1734x; 1.0634x over previous
//
#include <hip/hip_runtime.h>
#include <cstdint>
#include <cstddef>

// Keep ALL device FP math un-contracted (no implicit FMA) so FPS/kNN
// distance bits match the XLA-CPU reference exactly. Where FMA is wanted
// (conv inner loop, kNN dot) it is written explicitly with fmaf().
#pragma clang fp contract(off)

#define NB 8
#define NP 8192
#define NM 2048
#define NK 16
#define NCIN 64
#define NCF 67      // 3 + CIN
#define NCOUT 128
#define FTP 80      // padded feat_t row (floats), 320B aligned
typedef unsigned long long ull;
typedef __attribute__((ext_vector_type(2))) float f32x2;

// DPP-based wave64 f32 max reduce step: pure VALU (no LDS pipe).
template <int CTRL>
__device__ __forceinline__ float dpp_fmax(float v) {
  int o = __builtin_amdgcn_update_dpp(__float_as_int(v), __float_as_int(v),
                                      CTRL, 0xf, 0xf, false);
  return fmaxf(v, __int_as_float(o));
}
// After these 6 steps lane 63 holds max over all 64 lanes.
__device__ __forceinline__ float wave_fmax_to_lane63(float v) {
  v = dpp_fmax<0x111>(v);  // row_shr:1
  v = dpp_fmax<0x112>(v);  // row_shr:2
  v = dpp_fmax<0x114>(v);  // row_shr:4
  v = dpp_fmax<0x118>(v);  // row_shr:8
  v = dpp_fmax<0x142>(v);  // row_bcast15
  v = dpp_fmax<0x143>(v);  // row_bcast31
  return v;
}

// ---------------------------------------------------------------- FPS role
// Round-4 structure (measured floor: single barrier/iter, DPP value max +
// ballot first-lane argmax, u64 parity slots) with the dist loop rewritten
// on float2 pairs so clang can emit packed VOP3P (v_pk_mul_f32/v_pk_add_f32,
// 2 IEEE f32 ops per instruction, bit-identical per element). Tracking stays
// scalar in ascending index order -> identical first-index tie-break.
__device__ void fps_role(char* smem, int b, const float* __restrict__ xyz,
                         float* __restrict__ out_xyz) {
  float* sx = (float*)smem;
  float* sy = sx + NP;
  float* sz = sy + NP;
  ull* slot = (ull*)(sz + NP);   // [2][8]
  const int t = threadIdx.x;
  const float* P = xyz + (size_t)b * NP * 3;
  for (int i = t; i < NP; i += 512) {
    sx[i] = P[i * 3 + 0];
    sy[i] = P[i * 3 + 1];
    sz[i] = P[i * 3 + 2];
  }
  __syncthreads();
  f32x2 px[8], py[8], pz[8], dv[8];
  const int n0 = t * 16;
  {
    const f32x2* sx2 = (const f32x2*)sx;
    const f32x2* sy2 = (const f32x2*)sy;
    const f32x2* sz2 = (const f32x2*)sz;
#pragma unroll
    for (int j = 0; j < 8; ++j) {
      px[j] = sx2[t * 8 + j];
      py[j] = sy2[t * 8 + j];
      pz[j] = sz2[t * 8 + j];
      dv[j] = (f32x2){1e10f, 1e10f};
    }
  }
  int cur = 0;
  const int wid = t >> 6;
  const int lane = t & 63;
  float* outb = out_xyz + (size_t)b * NM * 3;
  for (int it = 0; it < NM; ++it) {
    const float cx = sx[cur], cy = sy[cur], cz = sz[cur];
    if (t == 0) {
      outb[it * 3 + 0] = cx;
      outb[it * 3 + 1] = cy;
      outb[it * 3 + 2] = cz;
    }
    const f32x2 c2x = (f32x2){cx, cx};
    const f32x2 c2y = (f32x2){cy, cy};
    const f32x2 c2z = (f32x2){cz, cz};
    float bv = -1.0f;
    int bn = 0;
#pragma unroll
    for (int j = 0; j < 8; ++j) {
      f32x2 dx = px[j] - c2x;
      f32x2 dy = py[j] - c2y;
      f32x2 dz = pz[j] - c2z;
      f32x2 d = dx * dx + dy * dy;   // contract(off): pk_mul/pk_add, no fma
      d = d + dz * dz;
      f32x2 nd = __builtin_elementwise_min(dv[j], d);
      dv[j] = nd;
      // scalar tracking, ascending element order == ascending index
      bool g0 = nd.x > bv;           // strict > keeps earliest on ties
      bv = g0 ? nd.x : bv;
      bn = g0 ? (n0 + 2 * j) : bn;
      bool g1 = nd.y > bv;
      bv = g1 ? nd.y : bv;
      bn = g1 ? (n0 + 2 * j + 1) : bn;
    }
    float wtop = wave_fmax_to_lane63(bv);
    float wmax = __int_as_float(__builtin_amdgcn_readlane(__float_as_int(wtop), 63));
    ull mset = __ballot(bv == wmax);
    int winlane = (int)(__ffsll(mset) - 1);
    int wn = __builtin_amdgcn_readlane(bn, winlane);
    if (lane == 0)
      slot[(it & 1) * 8 + wid] = (((ull)__float_as_uint(wmax)) << 32) | (unsigned)wn;
    __syncthreads();
    ull sv = slot[(it & 1) * 8 + (lane & 7)];
    float v2 = __uint_as_float((unsigned)(sv >> 32));
    int n2 = (int)(unsigned)(sv & 0xffffffffu);
    float gtop = wave_fmax_to_lane63(v2);
    float gmax = __int_as_float(__builtin_amdgcn_readlane(__float_as_int(gtop), 63));
    ull ms2 = __ballot(v2 == gmax);
    int wslot = (int)(__ffsll(ms2) - 1);
    cur = __builtin_amdgcn_readlane(n2, wslot);
  }
}

// ----------------------------------------------- transpose role (512 thr)
// feat_t[b][n][0..2]=xyz, [3..66]=features[:,n], [67..79]=0
__device__ void transpose_role(char* smem, int blk, const float* __restrict__ xyz,
                               const float* __restrict__ feats,
                               float* __restrict__ feat_t) {
  float (*tile)[81] = (float (*)[81])smem;  // 64x81, +1 pad
  const int b = blk >> 7;
  const int n0 = (blk & 127) << 6;
  const int t = threadIdx.x;
  if (t < 192) {
    float v = xyz[((size_t)b * NP + n0) * 3 + t];
    tile[t / 3][t % 3] = v;
  }
  const int cr = t >> 6;   // 0..7
  const int ln = t & 63;
  for (int c = cr; c < NCIN; c += 8) {
    tile[ln][3 + c] = feats[((size_t)b * NCIN + c) * NP + n0 + ln];
  }
  __syncthreads();
  float* dst = feat_t + ((size_t)b * NP + n0) * FTP;
  for (int i = t; i < 64 * FTP; i += 512) {
    int r = i / FTP, cc = i - r * FTP;
    dst[i] = (cc < NCF) ? tile[r][cc] : 0.0f;
  }
}

// ------------------------------------------------------ W transpose role
__device__ void wtrans_role(const float* __restrict__ W, float* __restrict__ Wt) {
  for (int i = threadIdx.x; i < NCF * NCOUT; i += 512) {
    int j = i >> 7, c = i & 127;
    Wt[i] = W[c * NCF + j];
  }
}

// --------------------------------------- prep: fps + transpose + wtrans
// Roles by blockIdx, ZERO inter-block communication (round-8 lesson: any
// cross-block protocol is radioactive under graph replay; independent
// co-scheduling is safe, verified rounds 10/11: prep == fps alone).
__global__ __launch_bounds__(512) void prep_kernel(
    const float* __restrict__ xyz, const float* __restrict__ feats,
    const float* __restrict__ W, float* __restrict__ out_xyz,
    float* __restrict__ feat_t, float* __restrict__ Wt) {
  __shared__ __align__(16) char smem[98432];  // fps: 96KB coords + 128B slots
  const int bi = blockIdx.x;
  if (bi < 8) {
    fps_role(smem, bi, xyz, out_xyz);
  } else if (bi < 8 + NB * 128) {
    transpose_role(smem, bi - 8, xyz, feats, feat_t);
  } else {
    wtrans_role(W, Wt);
  }
}

// ---------------------------------------------------------------- kNN
// ROUND-9/11 VERBATIM (measured-good). One wave per query; 4096 blocks ->
// 8 blocks/CU, full latency hiding.
__global__ __launch_bounds__(256) void knn_kernel(const float* __restrict__ xyz,
                                                  const float* __restrict__ new_xyz,
                                                  int* __restrict__ knn_idx) {
  __shared__ float tx_[1024], ty_[1024], tz_[1024], tp2_[1024];
  const int b = blockIdx.x >> 9;
  const int m = ((blockIdx.x & 511) << 2) + (threadIdx.x >> 6);
  const int lane = threadIdx.x & 63;
  const float* P = xyz + (size_t)b * NP * 3;
  const float* T = new_xyz + ((size_t)b * NM + m) * 3;
  const float qx = T[0], qy = T[1], qz = T[2];
  float q2 = qx * qx + qy * qy;
  q2 = q2 + qz * qz;
  ull r[16];
#pragma unroll
  for (int i = 0; i < 16; ++i) r[i] = ~0ull;
  for (int tile = 0; tile < 8; ++tile) {
    __syncthreads();
    for (int i = threadIdx.x; i < 3072; i += 256) {
      float v = P[tile * 3072 + i];
      int pt = i / 3, dc = i - pt * 3;
      float* dstp = (dc == 0) ? tx_ : ((dc == 1) ? ty_ : tz_);
      dstp[pt] = v;
    }
    __syncthreads();
    for (int i = threadIdx.x; i < 1024; i += 256) {
      float ax = tx_[i], ay = ty_[i], az = tz_[i];
      float p2 = ax * ax + ay * ay;   // same order as reference |p|^2
      p2 = p2 + az * az;
      tp2_[i] = p2;
    }
    __syncthreads();
    for (int i = 0; i < 16; ++i) {
      int p = (i << 6) + lane;
      float px = tx_[p], py = ty_[p], pz = tz_[p];
      float p2 = tp2_[p];
      float dot = fmaf(pz, qz, fmaf(py, qy, px * qx));
      float s1 = q2 + p2;
      float s2 = 2.0f * dot;
      float d = s1 - s2;
      unsigned db = __float_as_uint(d);
      db = ((int)db < 0) ? ~db : (db | 0x80000000u);  // monotone map (d can round < 0)
      ull key = ((ull)db << 32) | (unsigned)(tile * 1024 + p);
      if (key < r[15]) {
#pragma unroll
        for (int s = 0; s < 16; ++s) {
          ull lo = (key < r[s]) ? key : r[s];
          ull hi = (key < r[s]) ? r[s] : key;
          r[s] = lo;
          key = hi;
        }
      }
    }
  }
  // merge 64 sorted lists of 16 -> global top-16
  const int out_base = ((b * NM + m) << 4);
#pragma unroll 1
  for (int k = 0; k < NK; ++k) {
    ull best = r[0];
#pragma unroll
    for (int s = 1; s < 64; s <<= 1) {
      ull o = __shfl_xor(best, s, 64);
      best = (o < best) ? o : best;
    }
    if (lane == 0) knn_idx[out_base + k] = (int)(unsigned)(best & 0xffffffffu);
    if (r[0] == best) {  // unique keys: exactly one winner advances
#pragma unroll
      for (int s = 0; s < 15; ++s) r[s] = r[s + 1];
      r[15] = ~0ull;
    }
  }
}

// ------------------------------------------- gather + 1x1 conv + minmax + stats
// Block: 8 m's (128 neighbor columns). LDS: Wt[67][128] + data[68][128].
// partials layout: [c][2048] rows (sum c<128, sumsq 128+c) for coalesced
// bnstats reduction.
__global__ __launch_bounds__(256) void conv_kernel(const float* __restrict__ feat_t,
                                                   const int* __restrict__ knn_idx,
                                                   const float* __restrict__ Wt,
                                                   float* __restrict__ ymax,
                                                   float* __restrict__ ymin,
                                                   float* __restrict__ partials) {
  __shared__ float wl[NCF * 128];
  __shared__ float data[68 * 128];
  __shared__ int sidx[128];
  const int blk = blockIdx.x;  // 2048
  const int b = blk >> 8;
  const int m0 = (blk & 255) << 3;
  const int t = threadIdx.x;
  for (int i = t; i < NCF * 128; i += 256) wl[i] = Wt[i];
  if (t < 128) sidx[t] = knn_idx[((b * NM + m0) << 4) + t];
  __syncthreads();
  const int q = t & 3;
  for (int cc = t >> 2; cc < 128; cc += 64) {
    int n = sidx[cc];
    const float* src = feat_t + ((size_t)(b * NP + n)) * FTP + q * 20;
    float4 v0 = ((const float4*)src)[0];
    float4 v1 = ((const float4*)src)[1];
    float4 v2 = ((const float4*)src)[2];
    float4 v3 = ((const float4*)src)[3];
    float4 v4 = ((const float4*)src)[4];
    float vv[20] = {v0.x, v0.y, v0.z, v0.w, v1.x, v1.y, v1.z, v1.w,
                    v2.x, v2.y, v2.z, v2.w, v3.x, v3.y, v3.z, v3.w,
                    v4.x, v4.y, v4.z, v4.w};
    const int jb = q * 20;
#pragma unroll
    for (int u = 0; u < 20; ++u) {
      int j = jb + u;
      if (j < 68) data[j * 128 + cc] = vv[u];
    }
  }
  __syncthreads();
  const int colg = t & 31, cg = t >> 5;
  const int c0 = cg << 4, col0 = colg << 2;
  float acc[16][4];
#pragma unroll
  for (int a = 0; a < 16; ++a)
#pragma unroll
    for (int w = 0; w < 4; ++w) acc[a][w] = 0.0f;
  for (int j = 0; j < NCF; ++j) {
    const float4 dvv = *(const float4*)&data[j * 128 + col0];
    const float4 w0 = *(const float4*)&wl[j * 128 + c0 + 0];
    const float4 w1 = *(const float4*)&wl[j * 128 + c0 + 4];
    const float4 w2 = *(const float4*)&wl[j * 128 + c0 + 8];
    const float4 w3 = *(const float4*)&wl[j * 128 + c0 + 12];
    float wv[16] = {w0.x, w0.y, w0.z, w0.w, w1.x, w1.y, w1.z, w1.w,
                    w2.x, w2.y, w2.z, w2.w, w3.x, w3.y, w3.z, w3.w};
    float dd[4] = {dvv.x, dvv.y, dvv.z, dvv.w};
#pragma unroll
    for (int a = 0; a < 16; ++a)
#pragma unroll
      for (int w = 0; w < 4; ++w) acc[a][w] = fmaf(wv[a], dd[w], acc[a][w]);
  }
  const int mg = m0 + (colg >> 2);
#pragma unroll 1
  for (int a = 0; a < 16; ++a) {
    float x0 = acc[a][0], x1 = acc[a][1], x2 = acc[a][2], x3 = acc[a][3];
    float mx = fmaxf(fmaxf(x0, x1), fmaxf(x2, x3));
    float mn = fminf(fminf(x0, x1), fminf(x2, x3));
    float sm = (x0 + x1) + (x2 + x3);
    float sq = fmaf(x0, x0, fmaf(x1, x1, fmaf(x2, x2, x3 * x3)));
    float o;
    o = __shfl_xor(mx, 1, 64); mx = fmaxf(mx, o);
    o = __shfl_xor(mx, 2, 64); mx = fmaxf(mx, o);
    o = __shfl_xor(mn, 1, 64); mn = fminf(mn, o);
    o = __shfl_xor(mn, 2, 64); mn = fminf(mn, o);
#pragma unroll
    for (int s2 = 1; s2 < 32; s2 <<= 1) {
      sm += __shfl_xor(sm, s2, 64);
      sq += __shfl_xor(sq, s2, 64);
    }
    const int c = c0 + a;
    if ((colg & 3) == 0) {
      ymax[((size_t)b * NCOUT + c) * NM + mg] = mx;
      ymin[((size_t)b * NCOUT + c) * NM + mg] = mn;
    }
    if (colg == 0) {
      partials[(size_t)c * 2048 + blk] = sm;
      partials[(size_t)(128 + c) * 2048 + blk] = sq;
    }
  }
}

// ------------------------------------------------------- BN stats finalize
// 128 blocks (one per channel): coalesced row sums in double, LDS tree.
__global__ __launch_bounds__(256) void bnstats_kernel(const float* __restrict__ partials,
                                                      const float* __restrict__ gamma,
                                                      const float* __restrict__ beta,
                                                      float* __restrict__ chanAB) {
  __shared__ double sbuf[256];
  const int c = blockIdx.x;
  const int t = threadIdx.x;
  const float* rowS = partials + (size_t)c * 2048;
  const float* rowQ = partials + (size_t)(128 + c) * 2048;
  double a1 = 0.0, a2 = 0.0;
  for (int i = t; i < 2048; i += 256) {
    a1 += (double)rowS[i];
    a2 += (double)rowQ[i];
  }
  sbuf[t] = a1;
  __syncthreads();
  for (int off = 128; off; off >>= 1) {
    if (t < off) sbuf[t] += sbuf[t + off];
    __syncthreads();
  }
  const double sum1 = sbuf[0];
  __syncthreads();
  sbuf[t] = a2;
  __syncthreads();
  for (int off = 128; off; off >>= 1) {
    if (t < off) sbuf[t] += sbuf[t + off];
    __syncthreads();
  }
  const double sum2 = sbuf[0];
  if (t == 0) {
    const double inv = 1.0 / 262144.0;  // B*M*K
    double mean = sum1 * inv;
    double var = sum2 * inv - mean * mean;
    float a = gamma[c] * (float)(1.0 / sqrt(var + 1e-5));
    float bb = beta[c] - (float)mean * a;
    chanAB[c] = a;
    chanAB[128 + c] = bb;
  }
}

// ------------------------------------------------- normalize + relu + pool
// max_k relu(a*y+b) = relu(a*(a>0 ? ymax : ymin) + b)
__global__ __launch_bounds__(256) void final_kernel(const float* __restrict__ ymax,
                                                    const float* __restrict__ ymin,
                                                    const float* __restrict__ chanAB,
                                                    float* __restrict__ out1) {
  const int i = blockIdx.x * 256 + threadIdx.x;
  const int c = (i >> 11) & 127;
  const float a = chanAB[c], bb = chanAB[128 + c];
  const float v = (a > 0.0f) ? ymax[i] : ymin[i];
  out1[i] = fmaxf(fmaf(a, v, bb), 0.0f);
}

extern "C" void kernel_launch(void* const* d_in, const int* in_sizes, int n_in,
                              void* d_out, int out_size, void* d_ws, size_t ws_size,
                              hipStream_t stream) {
  (void)in_sizes; (void)n_in; (void)out_size; (void)ws_size;
  const float* xyz = (const float*)d_in[0];
  const float* feats = (const float*)d_in[1];
  const float* W = (const float*)d_in[2];
  const float* gamma = (const float*)d_in[3];
  const float* beta = (const float*)d_in[4];
  float* out = (float*)d_out;
  float* out_xyz = out;                 // (B,M,3)
  float* out_pooled = out + NB * NM * 3;

  char* ws = (char*)d_ws;
  int* knn_idx = (int*)ws;                                       // 1 MB
  float* feat_t = (float*)(ws + 1048576);                        // 20.97 MB
  float* ymaxp = (float*)(ws + 1048576 + 20971520);              // 8.39 MB
  float* yminp = ymaxp + (size_t)NB * NCOUT * NM;                // 8.39 MB
  float* partials = yminp + (size_t)NB * NCOUT * NM;             // 2 MB (256x2048)
  float* chanAB = partials + 256 * 2048;                         // 1 KB
  float* Wt = chanAB + 256;                                      // 34 KB

  hipLaunchKernelGGL(prep_kernel, dim3(8 + NB * 128 + 1), dim3(512), 0, stream,
                     xyz, feats, W, out_xyz, feat_t, Wt);
  hipLaunchKernelGGL(knn_kernel, dim3(NB * 512), dim3(256), 0, stream,
                     xyz, out_xyz, knn_idx);
  hipLaunchKernelGGL(conv_kernel, dim3(2048), dim3(256), 0, stream,
                     feat_t, knn_idx, Wt, ymaxp, yminp, partials);
  hipLaunchKernelGGL(bnstats_kernel, dim3(128), dim3(256), 0, stream,
                     partials, gamma, beta, chanAB);
  hipLaunchKernelGGL(final_kernel, dim3((NB * NCOUT * NM) / 256), dim3(256), 0, stream,
                     ymaxp, yminp, chanAB, out_pooled);
}